// Round 11
// baseline (702.627 us; speedup 1.0000x reference)
//
#include <hip/hip_runtime.h>
#include <math.h>

// ---------------------------------------------------------------------------
// SeasonalFNO1D: B=64, T=8192, F=6, MODES=32, WIDTH=64, LAYERS=4, FC1=128, OUT=7
// x packed: u32 = (bf16_hi<<16)|bf16_lo (split-bf16, ~2^-16 rel).
// FUSED PIPELINE: producers of x (fc0dft_k, combine_mfma) also compute the next
// layer's pruned-DFT partial and unsafeAtomicAdd into f32 part[b][j][c].
// Round 11: combine drops the LDS input stage. Conv A-frags read DIRECT from
// global (coalesced b128; 4x wave dup filtered by L1/L2). LDS = 16 KiB
// transpose buffer only; 2 barriers/chunk (plain s_barrier post-conv is
// WAR-safe: compiler waitcnts before MFMA use guarantee loads completed);
// no manual vmcnt anywhere; DFT A-frags loaded in the DFT phase (saves VGPRs).
// WRITEX template: l=2 stores only the t=T-1 chunk (final_k reads that row).
// ---------------------------------------------------------------------------

constexpr int B = 64, T = 8192, F = 6, MODES = 32, C = 64, FC1N = 128, OUTN = 7;
constexpr int TMASK = T - 1;
constexpr int GCHF = 8;                  // fc0dft: 64-row chunks per block
constexpr int GCHC = 4;                  // combine: 64-row chunks per block
constexpr int OSTR = 68;                 // fc0dft outT row stride (u32)

typedef __attribute__((ext_vector_type(4))) float f32x4;
typedef __attribute__((ext_vector_type(8))) short s16x8;

__device__ __forceinline__ float gelu_exact(float v) {
    return 0.5f * v * (1.0f + erff(v * 0.70710678118654752f));
}
// A&S 7.1.26 erf, |eps| <= 1.5e-7
__device__ __forceinline__ float gelu_fast(float v) {
    float z = fabsf(v) * 0.70710678118654752f;
    float t = __builtin_amdgcn_rcpf(fmaf(0.3275911f, z, 1.0f));
    float p = fmaf(t, 1.061405429f, -1.453152027f);
    p = fmaf(t, p, 1.421413741f);
    p = fmaf(t, p, -0.284496736f);
    p = fmaf(t, p, 0.254829592f);
    p = p * t;
    float e = __expf(-z * z);
    float erfv = copysignf(fmaf(-p, e, 1.0f), v);
    return 0.5f * v * (1.0f + erfv);
}
__device__ __forceinline__ unsigned short bf16_rne(float f) {
    unsigned u = __float_as_uint(f);
    unsigned r = u + 0x7FFFu + ((u >> 16) & 1u);
    return (unsigned short)(r >> 16);
}
__device__ __forceinline__ float bf16_f(unsigned short h) {
    return __uint_as_float(((unsigned)h) << 16);
}
__device__ __forceinline__ unsigned pack_split(float v) {
    unsigned short hi = bf16_rne(v);
    float lo = v - bf16_f(hi);
    return (((unsigned)hi) << 16) | (unsigned)bf16_rne(lo);
}
__device__ __forceinline__ s16x8 u4_to_s8(uint4 v) {
    union { uint4 u; s16x8 s; } cv; cv.u = v; return cv.s;
}
__device__ __forceinline__ s16x8 hi8(uint4 p0, uint4 p1) {
    uint4 h;
    h.x = __byte_perm(p0.x, p0.y, 0x7632); h.y = __byte_perm(p0.z, p0.w, 0x7632);
    h.z = __byte_perm(p1.x, p1.y, 0x7632); h.w = __byte_perm(p1.z, p1.w, 0x7632);
    return u4_to_s8(h);
}
__device__ __forceinline__ s16x8 lo8(uint4 p0, uint4 p1) {
    uint4 h;
    h.x = __byte_perm(p0.x, p0.y, 0x5410); h.y = __byte_perm(p0.z, p0.w, 0x5410);
    h.z = __byte_perm(p1.x, p1.y, 0x5410); h.w = __byte_perm(p1.z, p1.w, 0x5410);
    return u4_to_s8(h);
}

// twdH/twdL[t][j]: j<32: cos(2*pi*j*t/T); j>=32: sin(2*pi*(j-32)*t/T), split bf16
__global__ void twdtab_k(unsigned short* __restrict__ twdH, unsigned short* __restrict__ twdL) {
    int i = blockIdx.x * 256 + threadIdx.x;
    int t = i >> 6, j = i & 63, k = j & 31;
    int m = (k * t) & TMASK;
    double th = 6.283185307179586476925286766559 * (double)m / (double)T;
    float v = (float)((j < 32) ? cos(th) : sin(th));
    unsigned short hi = bf16_rne(v);
    twdH[i] = hi;
    twdL[i] = bf16_rne(v - bf16_f(hi));
}

// twdTPH/L[j][t] split bf16 (DFT A-operand: lane m=j, contiguous t)
__global__ void twdtabT_k(unsigned short* __restrict__ twdTPH, unsigned short* __restrict__ twdTPL) {
    int i = blockIdx.x * 256 + threadIdx.x;   // 64*8192
    int j = i >> 13, t = i & TMASK, k = j & 31;
    int m = (k * t) & TMASK;
    double th = 6.283185307179586476925286766559 * (double)m / (double)T;
    float v = (float)((j < 32) ? cos(th) : sin(th));
    unsigned short hi = bf16_rne(v);
    twdTPH[i] = hi;
    twdTPL[i] = bf16_rne(v - bf16_f(hi));
}

// Fused fc0 + layer-0 DFT partial. grid (T/512, B), 256 thr.
__global__ void __launch_bounds__(256) fc0dft_k(const float* __restrict__ in,
                                                const float* __restrict__ w,
                                                const float* __restrict__ bias,
                                                const unsigned short* __restrict__ twdTPH,
                                                const unsigned short* __restrict__ twdTPL,
                                                unsigned* __restrict__ x,
                                                float* __restrict__ partF) {
    __shared__ unsigned outT[64 * OSTR];
    int b = blockIdx.y, tid = threadIdx.x;
    int wv = tid >> 6, lane = tid & 63;
    int l15 = lane & 15, quad = lane >> 4;
    size_t bT = (size_t)b * T;

    int rr = tid & 15, cg = (tid >> 4) * 4;
    float wl[F][4], bl[4];
#pragma unroll
    for (int f = 0; f < F; f++)
#pragma unroll
        for (int j = 0; j < 4; j++) wl[f][j] = w[f * C + cg + j];
#pragma unroll
    for (int j = 0; j < 4; j++) bl[j] = bias[cg + j];

    const unsigned short* atpH = twdTPH + (size_t)(wv * 16 + l15) * T;
    const unsigned short* atpL = twdTPL + (size_t)(wv * 16 + l15) * T;
    f32x4 dftacc[4];
#pragma unroll
    for (int nt = 0; nt < 4; nt++) dftacc[nt] = (f32x4){0.f, 0.f, 0.f, 0.f};

    int t0 = blockIdx.x * (64 * GCHF);
    for (int g = 0; g < GCHF; g++) {
        int tb = t0 + g * 64;
        // load all 4 input rows first (float2 x3 per row; row*24 B is 8-aligned)
        float2 rin[4][3];
#pragma unroll
        for (int i = 0; i < 4; i++) {
            const float2* ip2 = (const float2*)(in + ((size_t)b * T + tb + rr + i * 16) * F);
            rin[i][0] = ip2[0]; rin[i][1] = ip2[1]; rin[i][2] = ip2[2];
        }
        // DFT A prefetch
        s16x8 dAh0 = *(const s16x8*)(atpH + tb + quad * 8);
        s16x8 dAl0 = *(const s16x8*)(atpL + tb + quad * 8);
        s16x8 dAh1 = *(const s16x8*)(atpH + tb + 32 + quad * 8);
        s16x8 dAl1 = *(const s16x8*)(atpL + tb + 32 + quad * 8);
#pragma unroll
        for (int i = 0; i < 4; i++) {
            int r = rr + i * 16;
            int trow = tb + r;
            float i0 = rin[i][0].x, i1 = rin[i][0].y, i2 = rin[i][1].x;
            float i3 = rin[i][1].y, i4 = rin[i][2].x, i5 = rin[i][2].y;
            uint4 pk;
            unsigned pv[4];
#pragma unroll
            for (int j = 0; j < 4; j++) {
                float v = bl[j];
                v = fmaf(i0, wl[0][j], v); v = fmaf(i1, wl[1][j], v);
                v = fmaf(i2, wl[2][j], v); v = fmaf(i3, wl[3][j], v);
                v = fmaf(i4, wl[4][j], v); v = fmaf(i5, wl[5][j], v);
                pv[j] = pack_split(v);
            }
            pk.x = pv[0]; pk.y = pv[1]; pk.z = pv[2]; pk.w = pv[3];
            *(uint4*)(x + (bT + trow) * C + cg) = pk;
            outT[(cg + 0) * OSTR + r] = pv[0];
            outT[(cg + 1) * OSTR + r] = pv[1];
            outT[(cg + 2) * OSTR + r] = pv[2];
            outT[(cg + 3) * OSTR + r] = pv[3];
        }
        asm volatile("s_waitcnt lgkmcnt(0)\n\ts_barrier" ::: "memory");  // outT visible
#pragma unroll
        for (int ks = 0; ks < 2; ks++) {
            s16x8 ah = ks ? dAh1 : dAh0;
            s16x8 al = ks ? dAl1 : dAl0;
#pragma unroll
            for (int nt = 0; nt < 4; nt++) {
                const unsigned* bp = &outT[(nt * 16 + l15) * OSTR + ks * 32 + quad * 8];
                uint4 b0 = *(const uint4*)bp;
                uint4 b1 = *(const uint4*)(bp + 4);
                s16x8 bh = hi8(b0, b1), bl2 = lo8(b0, b1);
                dftacc[nt] = __builtin_amdgcn_mfma_f32_16x16x32_bf16(ah, bh, dftacc[nt], 0, 0, 0);
                dftacc[nt] = __builtin_amdgcn_mfma_f32_16x16x32_bf16(ah, bl2, dftacc[nt], 0, 0, 0);
                dftacc[nt] = __builtin_amdgcn_mfma_f32_16x16x32_bf16(al, bh, dftacc[nt], 0, 0, 0);
            }
        }
        asm volatile("s_waitcnt lgkmcnt(0)\n\ts_barrier" ::: "memory");  // outT reads done
    }
    float sgn = (wv >= 2) ? -1.f : 1.f;
#pragma unroll
    for (int nt = 0; nt < 4; nt++)
#pragma unroll
        for (int r = 0; r < 4; r++) {
            int j = wv * 16 + quad * 4 + r;
            unsafeAtomicAdd(&partF[((size_t)b * 64 + j) * 64 + nt * 16 + l15],
                            sgn * dftacc[nt][r]);
        }
}

// Fused mode_mix + bweights. grid (B, 4); block q handles modes q*8..q*8+7.
__global__ void __launch_bounds__(256) mixbw_k(const float* __restrict__ partF,
                                               const float* __restrict__ wr,
                                               const float* __restrict__ wi,
                                               const float* __restrict__ cw,
                                               float2* __restrict__ Y,
                                               unsigned short* __restrict__ Bw,
                                               int writeBw) {
    __shared__ float xr[32][64], xi[32][64];
    int b = blockIdx.x, q = blockIdx.y, tid = threadIdx.x;
    int o = tid & 63, ks = tid >> 6;
    const float* pb = partF + (size_t)b * 4096;
    for (int i = tid; i < 2048; i += 256) xr[i >> 6][i & 63] = pb[i];
    for (int i = tid; i < 2048; i += 256) xi[i >> 6][i & 63] = pb[2048 + i];
    __syncthreads();
    const float invT = 1.0f / (float)T;
#pragma unroll
    for (int s = 0; s < 2; s++) {
        int k = q * 8 + ks * 2 + s;
        float ar = 0.f, ai = 0.f;
        const float* wrk = wr + (size_t)k * 4096 + o;
        const float* wik = wi + (size_t)k * 4096 + o;
        for (int c = 0; c < 64; c++) {
            float wrr = wrk[(size_t)c * 64];
            float wii = wik[(size_t)c * 64];
            float Xr = xr[k][c], Xi = xi[k][c];
            ar = fmaf(Xr, wrr, ar); ar = fmaf(-Xi, wii, ar);
            ai = fmaf(Xr, wii, ai); ai = fmaf(Xi, wrr, ai);
        }
        Y[((size_t)b * MODES + k) * C + o] = make_float2(ar, ai);
        if (writeBw) {
            size_t base = ((size_t)b * C + o) * 256;
            float s0 = (k == 0) ? invT : 2.0f * invT;
            float w0 = s0 * ar;
            unsigned short h0 = bf16_rne(w0);
            Bw[base + k] = h0;
            Bw[base + 128 + k] = bf16_rne(w0 - bf16_f(h0));
            float w1 = (-2.0f * invT) * ai;
            unsigned short h1 = bf16_rne(w1);
            Bw[base + 32 + k] = h1;
            Bw[base + 160 + k] = bf16_rne(w1 - bf16_f(h1));
        }
    }
    if (writeBw && q == 0) {
        for (int i = tid; i < 4096; i += 256) {
            int c = i >> 6, oo = i & 63;
            float w = cw[(size_t)c * C + oo];
            unsigned short h = bf16_rne(w);
            Bw[((size_t)b * C + oo) * 256 + 64 + c] = h;
            Bw[((size_t)b * C + oo) * 256 + 192 + c] = bf16_rne(w - bf16_f(h));
        }
    }
}

// Fused irfft+conv+gelu + next-layer DFT partial. In-place on packed x.
// grid (T/(64*GCHC), B), 256 thr = 4 waves. Conv A-frags direct from global.
// LDS = 16 KiB transposed chunk (swizzle slot c*64 + (t ^ ((c&7)*4))).
// 2 barriers/chunk: plain s_barrier post-conv (WAR for in-place stores +
// outT reuse), lgkmcnt(0)+s_barrier post-transpose-write.
template <int WRITEX>
__global__ void __launch_bounds__(256) combine_mfma(unsigned* __restrict__ xp,
                                                    const unsigned short* __restrict__ twdH,
                                                    const unsigned short* __restrict__ twdL,
                                                    const unsigned short* __restrict__ twdTPH,
                                                    const unsigned short* __restrict__ twdTPL,
                                                    const unsigned short* __restrict__ Bw,
                                                    const float* __restrict__ cb,
                                                    float* __restrict__ partF) {
    __shared__ unsigned outT[4096];      // 16 KiB
    int b = blockIdx.y;
    int tid = threadIdx.x;
    int wv = tid >> 6, lane = tid & 63;
    int lm = lane & 15, quad = lane >> 4;
    int ncol = wv * 16 + lm;
    size_t bT = (size_t)b * T;
    int sA = (lm & 7) * 4;               // XOR swizzle, 4-granular

    const unsigned short* bwp = Bw + ((size_t)b * C + ncol) * 256 + quad * 8;
    s16x8 bf0 = *(const s16x8*)(bwp + 0);
    s16x8 bf1 = *(const s16x8*)(bwp + 32);
    s16x8 bf2 = *(const s16x8*)(bwp + 64);
    s16x8 bf3 = *(const s16x8*)(bwp + 96);
    s16x8 bf4 = *(const s16x8*)(bwp + 128);
    s16x8 bf5 = *(const s16x8*)(bwp + 160);
    s16x8 bf6 = *(const s16x8*)(bwp + 192);
    s16x8 bf7 = *(const s16x8*)(bwp + 224);
    float cbv = cb[ncol];

    const unsigned short* atpH = twdTPH + (size_t)(wv * 16 + lm) * T;
    const unsigned short* atpL = twdTPL + (size_t)(wv * 16 + lm) * T;
    f32x4 dftacc[4];
#pragma unroll
    for (int nt = 0; nt < 4; nt++) dftacc[nt] = (f32x4){0.f, 0.f, 0.f, 0.f};

    int g0 = blockIdx.x * GCHC;

#pragma unroll
    for (int g = 0; g < GCHC; g++) {
        int t0 = (g0 + g) * 64;
        f32x4 acc[4];
#pragma unroll
        for (int mt = 0; mt < 4; mt++) acc[mt] = (f32x4){0.f, 0.f, 0.f, 0.f};

        // conv phase: A = [cos|sin|x_hi|x_lo] direct from global
#pragma unroll
        for (int mt = 0; mt < 4; mt++) {
            int t = t0 + mt * 16 + lm;
            const unsigned short* thp = twdH + (size_t)t * C + quad * 8;
            const unsigned short* tlp = twdL + (size_t)t * C + quad * 8;
            const unsigned* xr = xp + (bT + t) * C + quad * 8;
            s16x8 a;
            a = *(const s16x8*)thp;
            acc[mt] = __builtin_amdgcn_mfma_f32_16x16x32_bf16(a, bf0, acc[mt], 0, 0, 0);
            acc[mt] = __builtin_amdgcn_mfma_f32_16x16x32_bf16(a, bf4, acc[mt], 0, 0, 0);
            a = *(const s16x8*)(thp + 32);
            acc[mt] = __builtin_amdgcn_mfma_f32_16x16x32_bf16(a, bf1, acc[mt], 0, 0, 0);
            acc[mt] = __builtin_amdgcn_mfma_f32_16x16x32_bf16(a, bf5, acc[mt], 0, 0, 0);
            uint4 p0 = *(const uint4*)xr;
            uint4 p1 = *(const uint4*)(xr + 4);
            a = hi8(p0, p1);
            acc[mt] = __builtin_amdgcn_mfma_f32_16x16x32_bf16(a, bf2, acc[mt], 0, 0, 0);
            acc[mt] = __builtin_amdgcn_mfma_f32_16x16x32_bf16(a, bf6, acc[mt], 0, 0, 0);
            uint4 p2 = *(const uint4*)(xr + 32);
            uint4 p3 = *(const uint4*)(xr + 36);
            a = hi8(p2, p3);
            acc[mt] = __builtin_amdgcn_mfma_f32_16x16x32_bf16(a, bf3, acc[mt], 0, 0, 0);
            acc[mt] = __builtin_amdgcn_mfma_f32_16x16x32_bf16(a, bf7, acc[mt], 0, 0, 0);
            a = *(const s16x8*)tlp;
            acc[mt] = __builtin_amdgcn_mfma_f32_16x16x32_bf16(a, bf0, acc[mt], 0, 0, 0);
            a = *(const s16x8*)(tlp + 32);
            acc[mt] = __builtin_amdgcn_mfma_f32_16x16x32_bf16(a, bf1, acc[mt], 0, 0, 0);
            a = lo8(p0, p1);
            acc[mt] = __builtin_amdgcn_mfma_f32_16x16x32_bf16(a, bf2, acc[mt], 0, 0, 0);
            a = lo8(p2, p3);
            acc[mt] = __builtin_amdgcn_mfma_f32_16x16x32_bf16(a, bf3, acc[mt], 0, 0, 0);
        }
        // barrier A: every wave's conv loads of chunk g are consumed (compiler
        // waitcnts before MFMA use) -> safe to overwrite x in place; also
        // guarantees prior chunk's DFT reads of outT are done.
        asm volatile("s_barrier" ::: "memory");

        // epilogue: gelu+pack; global stores (per WRITEX); transposed LDS write
#pragma unroll
        for (int mt = 0; mt < 4; mt++) {
            uint4 pk;
            unsigned pv[4];
#pragma unroll
            for (int r = 0; r < 4; r++) {
                int t = t0 + mt * 16 + quad * 4 + r;
                float v = acc[mt][r] + cbv;
                pv[r] = pack_split(gelu_fast(v));
                if (WRITEX) {
                    xp[(bT + t) * C + ncol] = pv[r];
                } else if (t0 == T - 64) {
                    xp[(bT + t) * C + ncol] = pv[r];
                }
            }
            pk.x = pv[0]; pk.y = pv[1]; pk.z = pv[2]; pk.w = pv[3];
            *(uint4*)(&outT[ncol * 64 + ((mt * 16 + quad * 4) ^ sA)]) = pk;
        }
        // barrier B: transpose visible (LDS only; stores stay in flight)
        asm volatile("s_waitcnt lgkmcnt(0)\n\ts_barrier" ::: "memory");

        // DFT partial over this chunk's NEW x (K=64); A from L2-hot twdTP
#pragma unroll
        for (int ks = 0; ks < 2; ks++) {
            s16x8 ah = *(const s16x8*)(atpH + t0 + ks * 32 + quad * 8);
            s16x8 al = *(const s16x8*)(atpL + t0 + ks * 32 + quad * 8);
#pragma unroll
            for (int nt = 0; nt < 4; nt++) {
                int cd = nt * 16 + lm;   // cd&7 == lm&7 -> swizzle sA
                const unsigned* bpb = outT + cd * 64;
                int tb0 = (ks * 32 + quad * 8) ^ sA;
                uint4 b0 = *(const uint4*)(bpb + tb0);
                uint4 b1 = *(const uint4*)(bpb + (tb0 ^ 4));
                s16x8 bh = hi8(b0, b1), bl2 = lo8(b0, b1);
                dftacc[nt] = __builtin_amdgcn_mfma_f32_16x16x32_bf16(ah, bh, dftacc[nt], 0, 0, 0);
                dftacc[nt] = __builtin_amdgcn_mfma_f32_16x16x32_bf16(ah, bl2, dftacc[nt], 0, 0, 0);
                dftacc[nt] = __builtin_amdgcn_mfma_f32_16x16x32_bf16(al, bh, dftacc[nt], 0, 0, 0);
            }
        }
    }
    float sgn = (wv >= 2) ? -1.f : 1.f;
#pragma unroll
    for (int nt = 0; nt < 4; nt++)
#pragma unroll
        for (int r = 0; r < 4; r++) {
            int j = wv * 16 + quad * 4 + r;
            unsafeAtomicAdd(&partF[((size_t)b * 64 + j) * 64 + nt * 16 + lm],
                            sgn * dftacc[nt][r]);
        }
}

// Layer 3 at t=T-1 only, then fc1+gelu, fc2. grid B, 128 threads.
__global__ void final_k(const unsigned* __restrict__ x3, const float2* __restrict__ Y3,
                        const float* __restrict__ cw, const float* __restrict__ cb,
                        const float* __restrict__ w1, const float* __restrict__ b1,
                        const float* __restrict__ w2, const float* __restrict__ b2,
                        float* __restrict__ out) {
    int b = blockIdx.x, tid = threadIdx.x;
    __shared__ float xrow[C];
    __shared__ float xl[C];
    __shared__ float h[FC1N];
    if (tid < C) {
        unsigned u = x3[((size_t)b * T + (T - 1)) * C + tid];
        xrow[tid] = __uint_as_float(u & 0xFFFF0000u) + __uint_as_float(u << 16);
    }
    __syncthreads();
    if (tid < C) {
        int o = tid;
        const float2* Yb = Y3 + (size_t)b * (MODES * C);
        float a2 = 0.f;
        for (int k = 1; k < MODES; k++) {
            float thk = 7.6699039394282067e-4f * (float)k;
            float cwv = cosf(thk), swv = -sinf(thk);
            float2 y = Yb[k * C + o];
            a2 = fmaf(y.x, cwv, a2);
            a2 = fmaf(-y.y, swv, a2);
        }
        float xf = (Yb[o].x + 2.f * a2) * (1.0f / (float)T);
        float cv = cb[o];
        for (int c = 0; c < C; c++) cv = fmaf(xrow[c], cw[c * C + o], cv);
        xl[o] = gelu_exact(xf + cv);
    }
    __syncthreads();
    {
        int j = tid;
        float acc = b1[j];
        for (int c = 0; c < C; c++) acc = fmaf(xl[c], w1[c * FC1N + j], acc);
        h[j] = gelu_exact(acc);
    }
    __syncthreads();
    if (tid < OUTN) {
        float acc = b2[tid];
        for (int j = 0; j < FC1N; j++) acc = fmaf(h[j], w2[j * OUTN + tid], acc);
        out[b * OUTN + tid] = acc;
    }
}

extern "C" void kernel_launch(void* const* d_in, const int* in_sizes, int n_in,
                              void* d_out, int out_size, void* d_ws, size_t ws_size,
                              hipStream_t stream) {
    const float* inp   = (const float*)d_in[0];
    const float* fc0_w = (const float*)d_in[1];
    const float* fc0_b = (const float*)d_in[2];
    const float* fwr   = (const float*)d_in[3];
    const float* fwi   = (const float*)d_in[4];
    const float* cw    = (const float*)d_in[5];
    const float* cb    = (const float*)d_in[6];
    const float* w1    = (const float*)d_in[7];
    const float* b1    = (const float*)d_in[8];
    const float* w2    = (const float*)d_in[9];
    const float* b2    = (const float*)d_in[10];
    float* out = (float*)d_out;

    // Workspace layout (total 142,606,336 B <= proven 143,654,912)
    char* ws = (char*)d_ws;
    unsigned* x = (unsigned*)ws;                                  // 134,217,728
    size_t off = (size_t)B * T * C * sizeof(unsigned);
    float* partF = (float*)(ws + off);                            //   1,048,576
    const size_t PART_BYTES = (size_t)B * 64 * 64 * sizeof(float);
    off += PART_BYTES;
    float2* Y = (float2*)(ws + off);                              //   1,048,576
    off += (size_t)B * MODES * C * sizeof(float2);
    unsigned short* twdH = (unsigned short*)(ws + off);           //   1,048,576
    off += (size_t)T * C * sizeof(unsigned short);
    unsigned short* twdL = (unsigned short*)(ws + off);           //   1,048,576
    off += (size_t)T * C * sizeof(unsigned short);
    unsigned short* twdTPH = (unsigned short*)(ws + off);         //   1,048,576
    off += (size_t)64 * T * sizeof(unsigned short);
    unsigned short* twdTPL = (unsigned short*)(ws + off);         //   1,048,576
    off += (size_t)64 * T * sizeof(unsigned short);
    unsigned short* Bw = (unsigned short*)(ws + off);             //   2,097,152
    off += (size_t)B * C * 256 * sizeof(unsigned short);

    twdtab_k<<<(T * C) / 256, 256, 0, stream>>>(twdH, twdL);
    twdtabT_k<<<(64 * T) / 256, 256, 0, stream>>>(twdTPH, twdTPL);

    hipMemsetAsync(partF, 0, PART_BYTES, stream);
    fc0dft_k<<<dim3(T / (64 * GCHF), B), 256, 0, stream>>>(inp, fc0_w, fc0_b,
                                                           twdTPH, twdTPL, x, partF);

    for (int l = 0; l < 4; l++) {
        mixbw_k<<<dim3(B, 4), 256, 0, stream>>>(partF, fwr + (size_t)l * MODES * C * C,
                                                fwi + (size_t)l * MODES * C * C,
                                                cw + (size_t)l * C * C, Y, Bw,
                                                (l < 3) ? 1 : 0);
        if (l < 3) {
            hipMemsetAsync(partF, 0, PART_BYTES, stream);
            if (l == 2)
                combine_mfma<0><<<dim3(T / (64 * GCHC), B), 256, 0, stream>>>(
                    x, twdH, twdL, twdTPH, twdTPL, Bw, cb + (size_t)l * C, partF);
            else
                combine_mfma<1><<<dim3(T / (64 * GCHC), B), 256, 0, stream>>>(
                    x, twdH, twdL, twdTPH, twdTPL, Bw, cb + (size_t)l * C, partF);
        }
    }
    final_k<<<B, FC1N, 0, stream>>>(x, Y, cw + (size_t)3 * C * C, cb + (size_t)3 * C,
                                    w1, b1, w2, b2, out);
}

// Round 12
// 521.554 us; speedup vs baseline: 1.3472x; 1.3472x over previous
//
#include <hip/hip_runtime.h>
#include <math.h>

// ---------------------------------------------------------------------------
// SeasonalFNO1D: B=64, T=8192, F=6, MODES=32, WIDTH=64, LAYERS=4, FC1=128, OUT=7
// x packed: u32 = (bf16_hi<<16)|bf16_lo (split-bf16, ~2^-16 rel).
// FUSED PIPELINE: producers of x (fc0dft_k, combine_mfma) also compute the next
// layer's pruned-DFT partial and unsafeAtomicAdd into f32 part[b][j][c].
// Round 12: REVERT combine to round-10 (async global_load_lds double-buffer;
// round-11's direct-global A-frags were latency-exposed: 196 µs vs 115).
// LESSON: MFMA A-operands must come from LDS/regs, never raw global loads.
// Only change vs round 10: fc0dft GCHF 8->4 (1024->2048 blocks, was
// grid-starved at 4 blocks/CU with LDS allowing 9).
// ---------------------------------------------------------------------------

constexpr int B = 64, T = 8192, F = 6, MODES = 32, C = 64, FC1N = 128, OUTN = 7;
constexpr int TMASK = T - 1;
constexpr int GCHF = 4;                  // fc0dft: 64-row chunks per block
constexpr int GCHC = 4;                  // combine: 64-row chunks per block
constexpr int OSTR = 68;                 // fc0dft outT row stride (u32)

typedef __attribute__((ext_vector_type(4))) float f32x4;
typedef __attribute__((ext_vector_type(8))) short s16x8;
typedef const __attribute__((address_space(1))) unsigned* gas_ptr;
typedef __attribute__((address_space(3))) unsigned* las_ptr;

__device__ __forceinline__ float gelu_exact(float v) {
    return 0.5f * v * (1.0f + erff(v * 0.70710678118654752f));
}
// A&S 7.1.26 erf, |eps| <= 1.5e-7
__device__ __forceinline__ float gelu_fast(float v) {
    float z = fabsf(v) * 0.70710678118654752f;
    float t = __builtin_amdgcn_rcpf(fmaf(0.3275911f, z, 1.0f));
    float p = fmaf(t, 1.061405429f, -1.453152027f);
    p = fmaf(t, p, 1.421413741f);
    p = fmaf(t, p, -0.284496736f);
    p = fmaf(t, p, 0.254829592f);
    p = p * t;
    float e = __expf(-z * z);
    float erfv = copysignf(fmaf(-p, e, 1.0f), v);
    return 0.5f * v * (1.0f + erfv);
}
__device__ __forceinline__ unsigned short bf16_rne(float f) {
    unsigned u = __float_as_uint(f);
    unsigned r = u + 0x7FFFu + ((u >> 16) & 1u);
    return (unsigned short)(r >> 16);
}
__device__ __forceinline__ float bf16_f(unsigned short h) {
    return __uint_as_float(((unsigned)h) << 16);
}
__device__ __forceinline__ unsigned pack_split(float v) {
    unsigned short hi = bf16_rne(v);
    float lo = v - bf16_f(hi);
    return (((unsigned)hi) << 16) | (unsigned)bf16_rne(lo);
}
__device__ __forceinline__ s16x8 u4_to_s8(uint4 v) {
    union { uint4 u; s16x8 s; } cv; cv.u = v; return cv.s;
}
__device__ __forceinline__ s16x8 hi8(uint4 p0, uint4 p1) {
    uint4 h;
    h.x = __byte_perm(p0.x, p0.y, 0x7632); h.y = __byte_perm(p0.z, p0.w, 0x7632);
    h.z = __byte_perm(p1.x, p1.y, 0x7632); h.w = __byte_perm(p1.z, p1.w, 0x7632);
    return u4_to_s8(h);
}
__device__ __forceinline__ s16x8 lo8(uint4 p0, uint4 p1) {
    uint4 h;
    h.x = __byte_perm(p0.x, p0.y, 0x5410); h.y = __byte_perm(p0.z, p0.w, 0x5410);
    h.z = __byte_perm(p1.x, p1.y, 0x5410); h.w = __byte_perm(p1.z, p1.w, 0x5410);
    return u4_to_s8(h);
}

// twdH/twdL[t][j]: j<32: cos(2*pi*j*t/T); j>=32: sin(2*pi*(j-32)*t/T), split bf16
__global__ void twdtab_k(unsigned short* __restrict__ twdH, unsigned short* __restrict__ twdL) {
    int i = blockIdx.x * 256 + threadIdx.x;
    int t = i >> 6, j = i & 63, k = j & 31;
    int m = (k * t) & TMASK;
    double th = 6.283185307179586476925286766559 * (double)m / (double)T;
    float v = (float)((j < 32) ? cos(th) : sin(th));
    unsigned short hi = bf16_rne(v);
    twdH[i] = hi;
    twdL[i] = bf16_rne(v - bf16_f(hi));
}

// twdTPH/L[j][t] split bf16 (DFT A-operand: lane m=j, contiguous t)
__global__ void twdtabT_k(unsigned short* __restrict__ twdTPH, unsigned short* __restrict__ twdTPL) {
    int i = blockIdx.x * 256 + threadIdx.x;   // 64*8192
    int j = i >> 13, t = i & TMASK, k = j & 31;
    int m = (k * t) & TMASK;
    double th = 6.283185307179586476925286766559 * (double)m / (double)T;
    float v = (float)((j < 32) ? cos(th) : sin(th));
    unsigned short hi = bf16_rne(v);
    twdTPH[i] = hi;
    twdTPL[i] = bf16_rne(v - bf16_f(hi));
}

// Fused fc0 + layer-0 DFT partial. grid (T/(64*GCHF), B), 256 thr.
__global__ void __launch_bounds__(256) fc0dft_k(const float* __restrict__ in,
                                                const float* __restrict__ w,
                                                const float* __restrict__ bias,
                                                const unsigned short* __restrict__ twdTPH,
                                                const unsigned short* __restrict__ twdTPL,
                                                unsigned* __restrict__ x,
                                                float* __restrict__ partF) {
    __shared__ unsigned outT[64 * OSTR];
    int b = blockIdx.y, tid = threadIdx.x;
    int wv = tid >> 6, lane = tid & 63;
    int l15 = lane & 15, quad = lane >> 4;
    size_t bT = (size_t)b * T;

    int rr = tid & 15, cg = (tid >> 4) * 4;
    float wl[F][4], bl[4];
#pragma unroll
    for (int f = 0; f < F; f++)
#pragma unroll
        for (int j = 0; j < 4; j++) wl[f][j] = w[f * C + cg + j];
#pragma unroll
    for (int j = 0; j < 4; j++) bl[j] = bias[cg + j];

    const unsigned short* atpH = twdTPH + (size_t)(wv * 16 + l15) * T;
    const unsigned short* atpL = twdTPL + (size_t)(wv * 16 + l15) * T;
    f32x4 dftacc[4];
#pragma unroll
    for (int nt = 0; nt < 4; nt++) dftacc[nt] = (f32x4){0.f, 0.f, 0.f, 0.f};

    int t0 = blockIdx.x * (64 * GCHF);
    for (int g = 0; g < GCHF; g++) {
        int tb = t0 + g * 64;
        // load all 4 input rows first (float2 x3 per row; row*24 B is 8-aligned)
        float2 rin[4][3];
#pragma unroll
        for (int i = 0; i < 4; i++) {
            const float2* ip2 = (const float2*)(in + ((size_t)b * T + tb + rr + i * 16) * F);
            rin[i][0] = ip2[0]; rin[i][1] = ip2[1]; rin[i][2] = ip2[2];
        }
        // DFT A prefetch (before the x stores -> their later use never drains stores)
        s16x8 dAh0 = *(const s16x8*)(atpH + tb + quad * 8);
        s16x8 dAl0 = *(const s16x8*)(atpL + tb + quad * 8);
        s16x8 dAh1 = *(const s16x8*)(atpH + tb + 32 + quad * 8);
        s16x8 dAl1 = *(const s16x8*)(atpL + tb + 32 + quad * 8);
#pragma unroll
        for (int i = 0; i < 4; i++) {
            int r = rr + i * 16;
            int trow = tb + r;
            float i0 = rin[i][0].x, i1 = rin[i][0].y, i2 = rin[i][1].x;
            float i3 = rin[i][1].y, i4 = rin[i][2].x, i5 = rin[i][2].y;
            uint4 pk;
            unsigned pv[4];
#pragma unroll
            for (int j = 0; j < 4; j++) {
                float v = bl[j];
                v = fmaf(i0, wl[0][j], v); v = fmaf(i1, wl[1][j], v);
                v = fmaf(i2, wl[2][j], v); v = fmaf(i3, wl[3][j], v);
                v = fmaf(i4, wl[4][j], v); v = fmaf(i5, wl[5][j], v);
                pv[j] = pack_split(v);
            }
            pk.x = pv[0]; pk.y = pv[1]; pk.z = pv[2]; pk.w = pv[3];
            *(uint4*)(x + (bT + trow) * C + cg) = pk;
            outT[(cg + 0) * OSTR + r] = pv[0];
            outT[(cg + 1) * OSTR + r] = pv[1];
            outT[(cg + 2) * OSTR + r] = pv[2];
            outT[(cg + 3) * OSTR + r] = pv[3];
        }
        asm volatile("s_waitcnt lgkmcnt(0)\n\ts_barrier" ::: "memory");  // outT visible (no vm drain)
#pragma unroll
        for (int ks = 0; ks < 2; ks++) {
            s16x8 ah = ks ? dAh1 : dAh0;
            s16x8 al = ks ? dAl1 : dAl0;
#pragma unroll
            for (int nt = 0; nt < 4; nt++) {
                const unsigned* bp = &outT[(nt * 16 + l15) * OSTR + ks * 32 + quad * 8];
                uint4 b0 = *(const uint4*)bp;
                uint4 b1 = *(const uint4*)(bp + 4);
                s16x8 bh = hi8(b0, b1), bl2 = lo8(b0, b1);
                dftacc[nt] = __builtin_amdgcn_mfma_f32_16x16x32_bf16(ah, bh, dftacc[nt], 0, 0, 0);
                dftacc[nt] = __builtin_amdgcn_mfma_f32_16x16x32_bf16(ah, bl2, dftacc[nt], 0, 0, 0);
                dftacc[nt] = __builtin_amdgcn_mfma_f32_16x16x32_bf16(al, bh, dftacc[nt], 0, 0, 0);
            }
        }
        asm volatile("s_waitcnt lgkmcnt(0)\n\ts_barrier" ::: "memory");  // outT reads done
    }
    float sgn = (wv >= 2) ? -1.f : 1.f;
#pragma unroll
    for (int nt = 0; nt < 4; nt++)
#pragma unroll
        for (int r = 0; r < 4; r++) {
            int j = wv * 16 + quad * 4 + r;
            unsafeAtomicAdd(&partF[((size_t)b * 64 + j) * 64 + nt * 16 + l15],
                            sgn * dftacc[nt][r]);
        }
}

// Fused mode_mix + bweights. grid (B, 4); block q handles modes q*8..q*8+7.
__global__ void __launch_bounds__(256) mixbw_k(const float* __restrict__ partF,
                                               const float* __restrict__ wr,
                                               const float* __restrict__ wi,
                                               const float* __restrict__ cw,
                                               float2* __restrict__ Y,
                                               unsigned short* __restrict__ Bw,
                                               int writeBw) {
    __shared__ float xr[32][64], xi[32][64];
    int b = blockIdx.x, q = blockIdx.y, tid = threadIdx.x;
    int o = tid & 63, ks = tid >> 6;
    const float* pb = partF + (size_t)b * 4096;
    for (int i = tid; i < 2048; i += 256) xr[i >> 6][i & 63] = pb[i];
    for (int i = tid; i < 2048; i += 256) xi[i >> 6][i & 63] = pb[2048 + i];
    __syncthreads();
    const float invT = 1.0f / (float)T;
#pragma unroll
    for (int s = 0; s < 2; s++) {
        int k = q * 8 + ks * 2 + s;
        float ar = 0.f, ai = 0.f;
        const float* wrk = wr + (size_t)k * 4096 + o;
        const float* wik = wi + (size_t)k * 4096 + o;
        for (int c = 0; c < 64; c++) {
            float wrr = wrk[(size_t)c * 64];
            float wii = wik[(size_t)c * 64];
            float Xr = xr[k][c], Xi = xi[k][c];
            ar = fmaf(Xr, wrr, ar); ar = fmaf(-Xi, wii, ar);
            ai = fmaf(Xr, wii, ai); ai = fmaf(Xi, wrr, ai);
        }
        Y[((size_t)b * MODES + k) * C + o] = make_float2(ar, ai);
        if (writeBw) {
            size_t base = ((size_t)b * C + o) * 256;
            float s0 = (k == 0) ? invT : 2.0f * invT;
            float w0 = s0 * ar;
            unsigned short h0 = bf16_rne(w0);
            Bw[base + k] = h0;
            Bw[base + 128 + k] = bf16_rne(w0 - bf16_f(h0));
            float w1 = (-2.0f * invT) * ai;
            unsigned short h1 = bf16_rne(w1);
            Bw[base + 32 + k] = h1;
            Bw[base + 160 + k] = bf16_rne(w1 - bf16_f(h1));
        }
    }
    if (writeBw && q == 0) {
        for (int i = tid; i < 4096; i += 256) {
            int c = i >> 6, oo = i & 63;
            float w = cw[(size_t)c * C + oo];
            unsigned short h = bf16_rne(w);
            Bw[((size_t)b * C + oo) * 256 + 64 + c] = h;
            Bw[((size_t)b * C + oo) * 256 + 192 + c] = bf16_rne(w - bf16_f(h));
        }
    }
}

// Fused irfft+conv+gelu + next-layer DFT partial. In-place on packed x.
// grid (T/(64*GCHC), B), 256 thr = 4 waves. WRITEX compile-time:
// WRITEX=1 -> round-8 codegen; WRITEX=0 -> store only the t=T-1 chunk.
template <int WRITEX>
__global__ void __launch_bounds__(256) combine_mfma(unsigned* __restrict__ xp,
                                                    const unsigned short* __restrict__ twdH,
                                                    const unsigned short* __restrict__ twdL,
                                                    const unsigned short* __restrict__ twdTPH,
                                                    const unsigned short* __restrict__ twdTPL,
                                                    const unsigned short* __restrict__ Bw,
                                                    const float* __restrict__ cb,
                                                    float* __restrict__ partF) {
    __shared__ unsigned xs[2][4096];     // 32 KiB
    int b = blockIdx.y;
    int tid = threadIdx.x;
    int wv = tid >> 6, lane = tid & 63;
    int lm = lane & 15, quad = lane >> 4;
    int ncol = wv * 16 + lm;
    size_t bT = (size_t)b * T;
    int sA = (lm & 7) * 4;               // XOR swizzle, 4-granular

    const unsigned short* bwp = Bw + ((size_t)b * C + ncol) * 256 + quad * 8;
    s16x8 bf0 = *(const s16x8*)(bwp + 0);
    s16x8 bf1 = *(const s16x8*)(bwp + 32);
    s16x8 bf2 = *(const s16x8*)(bwp + 64);
    s16x8 bf3 = *(const s16x8*)(bwp + 96);
    s16x8 bf4 = *(const s16x8*)(bwp + 128);
    s16x8 bf5 = *(const s16x8*)(bwp + 160);
    s16x8 bf6 = *(const s16x8*)(bwp + 192);
    s16x8 bf7 = *(const s16x8*)(bwp + 224);
    float cbv = cb[ncol];

    const unsigned short* atpH = twdTPH + (size_t)(wv * 16 + lm) * T;
    const unsigned short* atpL = twdTPL + (size_t)(wv * 16 + lm) * T;
    f32x4 dftacc[4];
#pragma unroll
    for (int nt = 0; nt < 4; nt++) dftacc[nt] = (f32x4){0.f, 0.f, 0.f, 0.f};

    int g0 = blockIdx.x * GCHC;
    const unsigned* cbase = xp + (bT + (size_t)g0 * 64) * C;

    // Gather offsets: LDS slot r*64+u holds logical col u ^ ((r&7)*4).
    int soff[4];
#pragma unroll
    for (int p = 0; p < 4; p++) {
        int L = tid * 4 + p * 1024;
        int r = L >> 6, cl = L & 63;
        soff[p] = r * 64 + (cl ^ ((r & 7) * 4));
    }
#pragma unroll
    for (int p = 0; p < 4; p++)
        __builtin_amdgcn_global_load_lds((gas_ptr)(cbase + soff[p]),
                                         (las_ptr)(&xs[0][tid * 4 + p * 1024]), 16, 0, 0);

#pragma unroll
    for (int g = 0; g < GCHC; g++) {
        int t0 = (g0 + g) * 64;
        // barrier 1: staging-g visible; previous stores (if any) stay in flight.
        if (!WRITEX || g == 0) asm volatile("s_waitcnt vmcnt(0)\n\ts_barrier" ::: "memory");
        else                   asm volatile("s_waitcnt vmcnt(16)\n\ts_barrier" ::: "memory");

        // DFT A prefetch (issued before conv loads/stores; use never drains stores)
        s16x8 dAh0 = *(const s16x8*)(atpH + t0 + quad * 8);
        s16x8 dAl0 = *(const s16x8*)(atpL + t0 + quad * 8);
        s16x8 dAh1 = *(const s16x8*)(atpH + t0 + 32 + quad * 8);
        s16x8 dAl1 = *(const s16x8*)(atpL + t0 + 32 + quad * 8);

        unsigned* buf = xs[g & 1];
        f32x4 acc[4];
#pragma unroll
        for (int mt = 0; mt < 4; mt++) acc[mt] = (f32x4){0.f, 0.f, 0.f, 0.f};

#pragma unroll
        for (int mt = 0; mt < 4; mt++) {
            int rr = mt * 16 + lm;       // rr&7 == lm&7 -> swizzle sA
            int t = t0 + rr;
            const unsigned short* thp = twdH + (size_t)t * C + quad * 8;
            const unsigned short* tlp = twdL + (size_t)t * C + quad * 8;
            const unsigned* xrp = buf + rr * 64;
            int base0 = (quad * 8) ^ sA;
            s16x8 a;
            a = *(const s16x8*)thp;
            acc[mt] = __builtin_amdgcn_mfma_f32_16x16x32_bf16(a, bf0, acc[mt], 0, 0, 0);
            acc[mt] = __builtin_amdgcn_mfma_f32_16x16x32_bf16(a, bf4, acc[mt], 0, 0, 0);
            a = *(const s16x8*)(thp + 32);
            acc[mt] = __builtin_amdgcn_mfma_f32_16x16x32_bf16(a, bf1, acc[mt], 0, 0, 0);
            acc[mt] = __builtin_amdgcn_mfma_f32_16x16x32_bf16(a, bf5, acc[mt], 0, 0, 0);
            uint4 p0 = *(const uint4*)(xrp + base0);
            uint4 p1 = *(const uint4*)(xrp + (base0 ^ 4));
            a = hi8(p0, p1);
            acc[mt] = __builtin_amdgcn_mfma_f32_16x16x32_bf16(a, bf2, acc[mt], 0, 0, 0);
            acc[mt] = __builtin_amdgcn_mfma_f32_16x16x32_bf16(a, bf6, acc[mt], 0, 0, 0);
            uint4 p2 = *(const uint4*)(xrp + (base0 ^ 32));
            uint4 p3 = *(const uint4*)(xrp + (base0 ^ 36));
            a = hi8(p2, p3);
            acc[mt] = __builtin_amdgcn_mfma_f32_16x16x32_bf16(a, bf3, acc[mt], 0, 0, 0);
            acc[mt] = __builtin_amdgcn_mfma_f32_16x16x32_bf16(a, bf7, acc[mt], 0, 0, 0);
            a = *(const s16x8*)tlp;
            acc[mt] = __builtin_amdgcn_mfma_f32_16x16x32_bf16(a, bf0, acc[mt], 0, 0, 0);
            a = *(const s16x8*)(tlp + 32);
            acc[mt] = __builtin_amdgcn_mfma_f32_16x16x32_bf16(a, bf1, acc[mt], 0, 0, 0);
            a = lo8(p0, p1);
            acc[mt] = __builtin_amdgcn_mfma_f32_16x16x32_bf16(a, bf2, acc[mt], 0, 0, 0);
            a = lo8(p2, p3);
            acc[mt] = __builtin_amdgcn_mfma_f32_16x16x32_bf16(a, bf3, acc[mt], 0, 0, 0);
        }
        // barrier 2: all reads of buf done (LDS only; stores stay in flight)
        asm volatile("s_waitcnt lgkmcnt(0)\n\ts_barrier" ::: "memory");

        // staging for g+1 BEFORE the stores (makes vmcnt(16) at next top exact)
        if (g + 1 < GCHC) {
            const unsigned* nbase = cbase + (size_t)(g + 1) * 4096;
#pragma unroll
            for (int p = 0; p < 4; p++)
                __builtin_amdgcn_global_load_lds((gas_ptr)(nbase + soff[p]),
                                                 (las_ptr)(&xs[(g + 1) & 1][tid * 4 + p * 1024]),
                                                 16, 0, 0);
        }
        // epilogue: gelu+pack; transposed swizzled LDS write; stores per WRITEX
#pragma unroll
        for (int mt = 0; mt < 4; mt++) {
            uint4 pk;
            unsigned pv[4];
#pragma unroll
            for (int r = 0; r < 4; r++) {
                int t = t0 + mt * 16 + quad * 4 + r;
                float v = acc[mt][r] + cbv;
                pv[r] = pack_split(gelu_fast(v));
                if (WRITEX) {
                    xp[(bT + t) * C + ncol] = pv[r];
                } else if (t0 == T - 64) {
                    xp[(bT + t) * C + ncol] = pv[r];
                }
            }
            pk.x = pv[0]; pk.y = pv[1]; pk.z = pv[2]; pk.w = pv[3];
            *(uint4*)(&buf[ncol * 64 + ((mt * 16 + quad * 4) ^ sA)]) = pk;
        }
        // barrier 3: transpose visible (LDS only — stores remain in flight)
        asm volatile("s_waitcnt lgkmcnt(0)\n\ts_barrier" ::: "memory");

        // DFT partial over this chunk's NEW x (K=64); A from prefetched regs
#pragma unroll
        for (int ks = 0; ks < 2; ks++) {
            s16x8 ah = ks ? dAh1 : dAh0;
            s16x8 al = ks ? dAl1 : dAl0;
#pragma unroll
            for (int nt = 0; nt < 4; nt++) {
                int cd = nt * 16 + lm;   // cd&7 == lm&7 -> swizzle sA
                const unsigned* bpb = buf + cd * 64;
                int tb0 = (ks * 32 + quad * 8) ^ sA;
                uint4 b0 = *(const uint4*)(bpb + tb0);
                uint4 b1 = *(const uint4*)(bpb + (tb0 ^ 4));
                s16x8 bh = hi8(b0, b1), bl2 = lo8(b0, b1);
                dftacc[nt] = __builtin_amdgcn_mfma_f32_16x16x32_bf16(ah, bh, dftacc[nt], 0, 0, 0);
                dftacc[nt] = __builtin_amdgcn_mfma_f32_16x16x32_bf16(ah, bl2, dftacc[nt], 0, 0, 0);
                dftacc[nt] = __builtin_amdgcn_mfma_f32_16x16x32_bf16(al, bh, dftacc[nt], 0, 0, 0);
            }
        }
    }
    float sgn = (wv >= 2) ? -1.f : 1.f;
#pragma unroll
    for (int nt = 0; nt < 4; nt++)
#pragma unroll
        for (int r = 0; r < 4; r++) {
            int j = wv * 16 + quad * 4 + r;
            unsafeAtomicAdd(&partF[((size_t)b * 64 + j) * 64 + nt * 16 + lm],
                            sgn * dftacc[nt][r]);
        }
}

// Layer 3 at t=T-1 only, then fc1+gelu, fc2. grid B, 128 threads.
__global__ void final_k(const unsigned* __restrict__ x3, const float2* __restrict__ Y3,
                        const float* __restrict__ cw, const float* __restrict__ cb,
                        const float* __restrict__ w1, const float* __restrict__ b1,
                        const float* __restrict__ w2, const float* __restrict__ b2,
                        float* __restrict__ out) {
    int b = blockIdx.x, tid = threadIdx.x;
    __shared__ float xrow[C];
    __shared__ float xl[C];
    __shared__ float h[FC1N];
    if (tid < C) {
        unsigned u = x3[((size_t)b * T + (T - 1)) * C + tid];
        xrow[tid] = __uint_as_float(u & 0xFFFF0000u) + __uint_as_float(u << 16);
    }
    __syncthreads();
    if (tid < C) {
        int o = tid;
        const float2* Yb = Y3 + (size_t)b * (MODES * C);
        float a2 = 0.f;
        for (int k = 1; k < MODES; k++) {
            float thk = 7.6699039394282067e-4f * (float)k;
            float cwv = cosf(thk), swv = -sinf(thk);
            float2 y = Yb[k * C + o];
            a2 = fmaf(y.x, cwv, a2);
            a2 = fmaf(-y.y, swv, a2);
        }
        float xf = (Yb[o].x + 2.f * a2) * (1.0f / (float)T);
        float cv = cb[o];
        for (int c = 0; c < C; c++) cv = fmaf(xrow[c], cw[c * C + o], cv);
        xl[o] = gelu_exact(xf + cv);
    }
    __syncthreads();
    {
        int j = tid;
        float acc = b1[j];
        for (int c = 0; c < C; c++) acc = fmaf(xl[c], w1[c * FC1N + j], acc);
        h[j] = gelu_exact(acc);
    }
    __syncthreads();
    if (tid < OUTN) {
        float acc = b2[tid];
        for (int j = 0; j < FC1N; j++) acc = fmaf(h[j], w2[j * OUTN + tid], acc);
        out[b * OUTN + tid] = acc;
    }
}

extern "C" void kernel_launch(void* const* d_in, const int* in_sizes, int n_in,
                              void* d_out, int out_size, void* d_ws, size_t ws_size,
                              hipStream_t stream) {
    const float* inp   = (const float*)d_in[0];
    const float* fc0_w = (const float*)d_in[1];
    const float* fc0_b = (const float*)d_in[2];
    const float* fwr   = (const float*)d_in[3];
    const float* fwi   = (const float*)d_in[4];
    const float* cw    = (const float*)d_in[5];
    const float* cb    = (const float*)d_in[6];
    const float* w1    = (const float*)d_in[7];
    const float* b1    = (const float*)d_in[8];
    const float* w2    = (const float*)d_in[9];
    const float* b2    = (const float*)d_in[10];
    float* out = (float*)d_out;

    // Workspace layout (total 142,606,336 B <= proven 143,654,912)
    char* ws = (char*)d_ws;
    unsigned* x = (unsigned*)ws;                                  // 134,217,728
    size_t off = (size_t)B * T * C * sizeof(unsigned);
    float* partF = (float*)(ws + off);                            //   1,048,576
    const size_t PART_BYTES = (size_t)B * 64 * 64 * sizeof(float);
    off += PART_BYTES;
    float2* Y = (float2*)(ws + off);                              //   1,048,576
    off += (size_t)B * MODES * C * sizeof(float2);
    unsigned short* twdH = (unsigned short*)(ws + off);           //   1,048,576
    off += (size_t)T * C * sizeof(unsigned short);
    unsigned short* twdL = (unsigned short*)(ws + off);           //   1,048,576
    off += (size_t)T * C * sizeof(unsigned short);
    unsigned short* twdTPH = (unsigned short*)(ws + off);         //   1,048,576
    off += (size_t)64 * T * sizeof(unsigned short);
    unsigned short* twdTPL = (unsigned short*)(ws + off);         //   1,048,576
    off += (size_t)64 * T * sizeof(unsigned short);
    unsigned short* Bw = (unsigned short*)(ws + off);             //   2,097,152
    off += (size_t)B * C * 256 * sizeof(unsigned short);

    twdtab_k<<<(T * C) / 256, 256, 0, stream>>>(twdH, twdL);
    twdtabT_k<<<(64 * T) / 256, 256, 0, stream>>>(twdTPH, twdTPL);

    hipMemsetAsync(partF, 0, PART_BYTES, stream);
    fc0dft_k<<<dim3(T / (64 * GCHF), B), 256, 0, stream>>>(inp, fc0_w, fc0_b,
                                                           twdTPH, twdTPL, x, partF);

    for (int l = 0; l < 4; l++) {
        mixbw_k<<<dim3(B, 4), 256, 0, stream>>>(partF, fwr + (size_t)l * MODES * C * C,
                                                fwi + (size_t)l * MODES * C * C,
                                                cw + (size_t)l * C * C, Y, Bw,
                                                (l < 3) ? 1 : 0);
        if (l < 3) {
            hipMemsetAsync(partF, 0, PART_BYTES, stream);
            if (l == 2)
                combine_mfma<0><<<dim3(T / (64 * GCHC), B), 256, 0, stream>>>(
                    x, twdH, twdL, twdTPH, twdTPL, Bw, cb + (size_t)l * C, partF);
            else
                combine_mfma<1><<<dim3(T / (64 * GCHC), B), 256, 0, stream>>>(
                    x, twdH, twdL, twdTPH, twdTPL, Bw, cb + (size_t)l * C, partF);
        }
    }
    final_k<<<B, FC1N, 0, stream>>>(x, Y, cw + (size_t)3 * C * C, cb + (size_t)3 * C,
                                    w1, b1, w2, b2, out);
}

// Round 13
// 515.688 us; speedup vs baseline: 1.3625x; 1.0114x over previous
//
#include <hip/hip_runtime.h>
#include <math.h>

// ---------------------------------------------------------------------------
// SeasonalFNO1D: B=64, T=8192, F=6, MODES=32, WIDTH=64, LAYERS=4, FC1=128, OUT=7
// x packed: u32 = (bf16_hi<<16)|bf16_lo (split-bf16, ~2^-16 rel).
// FUSED PIPELINE: producers of x (fc0dft_k, combine_mfma) also compute the next
// layer's pruned-DFT partial and unsafeAtomicAdd into f32 part[b][j][c].
// Round 13: round-10 structure (GCHF=8, async dbuf staging, WRITEX template)
// + EPILOGUE HOIST: gelu+pack computed into registers BEFORE barrier 2
// (register-only, overlaps other waves' conv-MFMA); between barriers 2/3 only
// the store burst remains -> waves reach the DFT phase sooner. acc dies as pv
// is born -> VGPR-neutral (check VGPR_Count stays ~80; round-9 lesson).
// ---------------------------------------------------------------------------

constexpr int B = 64, T = 8192, F = 6, MODES = 32, C = 64, FC1N = 128, OUTN = 7;
constexpr int TMASK = T - 1;
constexpr int GCHF = 8;                  // fc0dft: 64-row chunks per block
constexpr int GCHC = 4;                  // combine: 64-row chunks per block
constexpr int OSTR = 68;                 // fc0dft outT row stride (u32)

typedef __attribute__((ext_vector_type(4))) float f32x4;
typedef __attribute__((ext_vector_type(8))) short s16x8;
typedef const __attribute__((address_space(1))) unsigned* gas_ptr;
typedef __attribute__((address_space(3))) unsigned* las_ptr;

__device__ __forceinline__ float gelu_exact(float v) {
    return 0.5f * v * (1.0f + erff(v * 0.70710678118654752f));
}
// A&S 7.1.26 erf, |eps| <= 1.5e-7
__device__ __forceinline__ float gelu_fast(float v) {
    float z = fabsf(v) * 0.70710678118654752f;
    float t = __builtin_amdgcn_rcpf(fmaf(0.3275911f, z, 1.0f));
    float p = fmaf(t, 1.061405429f, -1.453152027f);
    p = fmaf(t, p, 1.421413741f);
    p = fmaf(t, p, -0.284496736f);
    p = fmaf(t, p, 0.254829592f);
    p = p * t;
    float e = __expf(-z * z);
    float erfv = copysignf(fmaf(-p, e, 1.0f), v);
    return 0.5f * v * (1.0f + erfv);
}
__device__ __forceinline__ unsigned short bf16_rne(float f) {
    unsigned u = __float_as_uint(f);
    unsigned r = u + 0x7FFFu + ((u >> 16) & 1u);
    return (unsigned short)(r >> 16);
}
__device__ __forceinline__ float bf16_f(unsigned short h) {
    return __uint_as_float(((unsigned)h) << 16);
}
__device__ __forceinline__ unsigned pack_split(float v) {
    unsigned short hi = bf16_rne(v);
    float lo = v - bf16_f(hi);
    return (((unsigned)hi) << 16) | (unsigned)bf16_rne(lo);
}
__device__ __forceinline__ s16x8 u4_to_s8(uint4 v) {
    union { uint4 u; s16x8 s; } cv; cv.u = v; return cv.s;
}
__device__ __forceinline__ s16x8 hi8(uint4 p0, uint4 p1) {
    uint4 h;
    h.x = __byte_perm(p0.x, p0.y, 0x7632); h.y = __byte_perm(p0.z, p0.w, 0x7632);
    h.z = __byte_perm(p1.x, p1.y, 0x7632); h.w = __byte_perm(p1.z, p1.w, 0x7632);
    return u4_to_s8(h);
}
__device__ __forceinline__ s16x8 lo8(uint4 p0, uint4 p1) {
    uint4 h;
    h.x = __byte_perm(p0.x, p0.y, 0x5410); h.y = __byte_perm(p0.z, p0.w, 0x5410);
    h.z = __byte_perm(p1.x, p1.y, 0x5410); h.w = __byte_perm(p1.z, p1.w, 0x5410);
    return u4_to_s8(h);
}

// twdH/twdL[t][j]: j<32: cos(2*pi*j*t/T); j>=32: sin(2*pi*(j-32)*t/T), split bf16
__global__ void twdtab_k(unsigned short* __restrict__ twdH, unsigned short* __restrict__ twdL) {
    int i = blockIdx.x * 256 + threadIdx.x;
    int t = i >> 6, j = i & 63, k = j & 31;
    int m = (k * t) & TMASK;
    double th = 6.283185307179586476925286766559 * (double)m / (double)T;
    float v = (float)((j < 32) ? cos(th) : sin(th));
    unsigned short hi = bf16_rne(v);
    twdH[i] = hi;
    twdL[i] = bf16_rne(v - bf16_f(hi));
}

// twdTPH/L[j][t] split bf16 (DFT A-operand: lane m=j, contiguous t)
__global__ void twdtabT_k(unsigned short* __restrict__ twdTPH, unsigned short* __restrict__ twdTPL) {
    int i = blockIdx.x * 256 + threadIdx.x;   // 64*8192
    int j = i >> 13, t = i & TMASK, k = j & 31;
    int m = (k * t) & TMASK;
    double th = 6.283185307179586476925286766559 * (double)m / (double)T;
    float v = (float)((j < 32) ? cos(th) : sin(th));
    unsigned short hi = bf16_rne(v);
    twdTPH[i] = hi;
    twdTPL[i] = bf16_rne(v - bf16_f(hi));
}

// Fused fc0 + layer-0 DFT partial. grid (T/(64*GCHF), B), 256 thr.
__global__ void __launch_bounds__(256) fc0dft_k(const float* __restrict__ in,
                                                const float* __restrict__ w,
                                                const float* __restrict__ bias,
                                                const unsigned short* __restrict__ twdTPH,
                                                const unsigned short* __restrict__ twdTPL,
                                                unsigned* __restrict__ x,
                                                float* __restrict__ partF) {
    __shared__ unsigned outT[64 * OSTR];
    int b = blockIdx.y, tid = threadIdx.x;
    int wv = tid >> 6, lane = tid & 63;
    int l15 = lane & 15, quad = lane >> 4;
    size_t bT = (size_t)b * T;

    int rr = tid & 15, cg = (tid >> 4) * 4;
    float wl[F][4], bl[4];
#pragma unroll
    for (int f = 0; f < F; f++)
#pragma unroll
        for (int j = 0; j < 4; j++) wl[f][j] = w[f * C + cg + j];
#pragma unroll
    for (int j = 0; j < 4; j++) bl[j] = bias[cg + j];

    const unsigned short* atpH = twdTPH + (size_t)(wv * 16 + l15) * T;
    const unsigned short* atpL = twdTPL + (size_t)(wv * 16 + l15) * T;
    f32x4 dftacc[4];
#pragma unroll
    for (int nt = 0; nt < 4; nt++) dftacc[nt] = (f32x4){0.f, 0.f, 0.f, 0.f};

    int t0 = blockIdx.x * (64 * GCHF);
    for (int g = 0; g < GCHF; g++) {
        int tb = t0 + g * 64;
        // load all 4 input rows first (float2 x3 per row; row*24 B is 8-aligned)
        float2 rin[4][3];
#pragma unroll
        for (int i = 0; i < 4; i++) {
            const float2* ip2 = (const float2*)(in + ((size_t)b * T + tb + rr + i * 16) * F);
            rin[i][0] = ip2[0]; rin[i][1] = ip2[1]; rin[i][2] = ip2[2];
        }
        // DFT A prefetch (before the x stores -> their later use never drains stores)
        s16x8 dAh0 = *(const s16x8*)(atpH + tb + quad * 8);
        s16x8 dAl0 = *(const s16x8*)(atpL + tb + quad * 8);
        s16x8 dAh1 = *(const s16x8*)(atpH + tb + 32 + quad * 8);
        s16x8 dAl1 = *(const s16x8*)(atpL + tb + 32 + quad * 8);
#pragma unroll
        for (int i = 0; i < 4; i++) {
            int r = rr + i * 16;
            int trow = tb + r;
            float i0 = rin[i][0].x, i1 = rin[i][0].y, i2 = rin[i][1].x;
            float i3 = rin[i][1].y, i4 = rin[i][2].x, i5 = rin[i][2].y;
            uint4 pk;
            unsigned pv[4];
#pragma unroll
            for (int j = 0; j < 4; j++) {
                float v = bl[j];
                v = fmaf(i0, wl[0][j], v); v = fmaf(i1, wl[1][j], v);
                v = fmaf(i2, wl[2][j], v); v = fmaf(i3, wl[3][j], v);
                v = fmaf(i4, wl[4][j], v); v = fmaf(i5, wl[5][j], v);
                pv[j] = pack_split(v);
            }
            pk.x = pv[0]; pk.y = pv[1]; pk.z = pv[2]; pk.w = pv[3];
            *(uint4*)(x + (bT + trow) * C + cg) = pk;
            outT[(cg + 0) * OSTR + r] = pv[0];
            outT[(cg + 1) * OSTR + r] = pv[1];
            outT[(cg + 2) * OSTR + r] = pv[2];
            outT[(cg + 3) * OSTR + r] = pv[3];
        }
        asm volatile("s_waitcnt lgkmcnt(0)\n\ts_barrier" ::: "memory");  // outT visible (no vm drain)
#pragma unroll
        for (int ks = 0; ks < 2; ks++) {
            s16x8 ah = ks ? dAh1 : dAh0;
            s16x8 al = ks ? dAl1 : dAl0;
#pragma unroll
            for (int nt = 0; nt < 4; nt++) {
                const unsigned* bp = &outT[(nt * 16 + l15) * OSTR + ks * 32 + quad * 8];
                uint4 b0 = *(const uint4*)bp;
                uint4 b1 = *(const uint4*)(bp + 4);
                s16x8 bh = hi8(b0, b1), bl2 = lo8(b0, b1);
                dftacc[nt] = __builtin_amdgcn_mfma_f32_16x16x32_bf16(ah, bh, dftacc[nt], 0, 0, 0);
                dftacc[nt] = __builtin_amdgcn_mfma_f32_16x16x32_bf16(ah, bl2, dftacc[nt], 0, 0, 0);
                dftacc[nt] = __builtin_amdgcn_mfma_f32_16x16x32_bf16(al, bh, dftacc[nt], 0, 0, 0);
            }
        }
        asm volatile("s_waitcnt lgkmcnt(0)\n\ts_barrier" ::: "memory");  // outT reads done
    }
    float sgn = (wv >= 2) ? -1.f : 1.f;
#pragma unroll
    for (int nt = 0; nt < 4; nt++)
#pragma unroll
        for (int r = 0; r < 4; r++) {
            int j = wv * 16 + quad * 4 + r;
            unsafeAtomicAdd(&partF[((size_t)b * 64 + j) * 64 + nt * 16 + l15],
                            sgn * dftacc[nt][r]);
        }
}

// Fused mode_mix + bweights. grid (B, 4); block q handles modes q*8..q*8+7.
__global__ void __launch_bounds__(256) mixbw_k(const float* __restrict__ partF,
                                               const float* __restrict__ wr,
                                               const float* __restrict__ wi,
                                               const float* __restrict__ cw,
                                               float2* __restrict__ Y,
                                               unsigned short* __restrict__ Bw,
                                               int writeBw) {
    __shared__ float xr[32][64], xi[32][64];
    int b = blockIdx.x, q = blockIdx.y, tid = threadIdx.x;
    int o = tid & 63, ks = tid >> 6;
    const float* pb = partF + (size_t)b * 4096;
    for (int i = tid; i < 2048; i += 256) xr[i >> 6][i & 63] = pb[i];
    for (int i = tid; i < 2048; i += 256) xi[i >> 6][i & 63] = pb[2048 + i];
    __syncthreads();
    const float invT = 1.0f / (float)T;
#pragma unroll
    for (int s = 0; s < 2; s++) {
        int k = q * 8 + ks * 2 + s;
        float ar = 0.f, ai = 0.f;
        const float* wrk = wr + (size_t)k * 4096 + o;
        const float* wik = wi + (size_t)k * 4096 + o;
        for (int c = 0; c < 64; c++) {
            float wrr = wrk[(size_t)c * 64];
            float wii = wik[(size_t)c * 64];
            float Xr = xr[k][c], Xi = xi[k][c];
            ar = fmaf(Xr, wrr, ar); ar = fmaf(-Xi, wii, ar);
            ai = fmaf(Xr, wii, ai); ai = fmaf(Xi, wrr, ai);
        }
        Y[((size_t)b * MODES + k) * C + o] = make_float2(ar, ai);
        if (writeBw) {
            size_t base = ((size_t)b * C + o) * 256;
            float s0 = (k == 0) ? invT : 2.0f * invT;
            float w0 = s0 * ar;
            unsigned short h0 = bf16_rne(w0);
            Bw[base + k] = h0;
            Bw[base + 128 + k] = bf16_rne(w0 - bf16_f(h0));
            float w1 = (-2.0f * invT) * ai;
            unsigned short h1 = bf16_rne(w1);
            Bw[base + 32 + k] = h1;
            Bw[base + 160 + k] = bf16_rne(w1 - bf16_f(h1));
        }
    }
    if (writeBw && q == 0) {
        for (int i = tid; i < 4096; i += 256) {
            int c = i >> 6, oo = i & 63;
            float w = cw[(size_t)c * C + oo];
            unsigned short h = bf16_rne(w);
            Bw[((size_t)b * C + oo) * 256 + 64 + c] = h;
            Bw[((size_t)b * C + oo) * 256 + 192 + c] = bf16_rne(w - bf16_f(h));
        }
    }
}

// Fused irfft+conv+gelu + next-layer DFT partial. In-place on packed x.
// grid (T/(64*GCHC), B), 256 thr = 4 waves. WRITEX compile-time.
// Epilogue VALU (gelu+pack) hoisted ABOVE barrier 2 (register-only work);
// only the store burst sits between barriers 2 and 3.
template <int WRITEX>
__global__ void __launch_bounds__(256) combine_mfma(unsigned* __restrict__ xp,
                                                    const unsigned short* __restrict__ twdH,
                                                    const unsigned short* __restrict__ twdL,
                                                    const unsigned short* __restrict__ twdTPH,
                                                    const unsigned short* __restrict__ twdTPL,
                                                    const unsigned short* __restrict__ Bw,
                                                    const float* __restrict__ cb,
                                                    float* __restrict__ partF) {
    __shared__ unsigned xs[2][4096];     // 32 KiB
    int b = blockIdx.y;
    int tid = threadIdx.x;
    int wv = tid >> 6, lane = tid & 63;
    int lm = lane & 15, quad = lane >> 4;
    int ncol = wv * 16 + lm;
    size_t bT = (size_t)b * T;
    int sA = (lm & 7) * 4;               // XOR swizzle, 4-granular

    const unsigned short* bwp = Bw + ((size_t)b * C + ncol) * 256 + quad * 8;
    s16x8 bf0 = *(const s16x8*)(bwp + 0);
    s16x8 bf1 = *(const s16x8*)(bwp + 32);
    s16x8 bf2 = *(const s16x8*)(bwp + 64);
    s16x8 bf3 = *(const s16x8*)(bwp + 96);
    s16x8 bf4 = *(const s16x8*)(bwp + 128);
    s16x8 bf5 = *(const s16x8*)(bwp + 160);
    s16x8 bf6 = *(const s16x8*)(bwp + 192);
    s16x8 bf7 = *(const s16x8*)(bwp + 224);
    float cbv = cb[ncol];

    const unsigned short* atpH = twdTPH + (size_t)(wv * 16 + lm) * T;
    const unsigned short* atpL = twdTPL + (size_t)(wv * 16 + lm) * T;
    f32x4 dftacc[4];
#pragma unroll
    for (int nt = 0; nt < 4; nt++) dftacc[nt] = (f32x4){0.f, 0.f, 0.f, 0.f};

    int g0 = blockIdx.x * GCHC;
    const unsigned* cbase = xp + (bT + (size_t)g0 * 64) * C;

    // Gather offsets: LDS slot r*64+u holds logical col u ^ ((r&7)*4).
    int soff[4];
#pragma unroll
    for (int p = 0; p < 4; p++) {
        int L = tid * 4 + p * 1024;
        int r = L >> 6, cl = L & 63;
        soff[p] = r * 64 + (cl ^ ((r & 7) * 4));
    }
#pragma unroll
    for (int p = 0; p < 4; p++)
        __builtin_amdgcn_global_load_lds((gas_ptr)(cbase + soff[p]),
                                         (las_ptr)(&xs[0][tid * 4 + p * 1024]), 16, 0, 0);

#pragma unroll
    for (int g = 0; g < GCHC; g++) {
        int t0 = (g0 + g) * 64;
        // barrier 1: staging-g visible; previous stores (if any) stay in flight.
        if (!WRITEX || g == 0) asm volatile("s_waitcnt vmcnt(0)\n\ts_barrier" ::: "memory");
        else                   asm volatile("s_waitcnt vmcnt(16)\n\ts_barrier" ::: "memory");

        // DFT A prefetch (issued before conv loads/stores; use never drains stores)
        s16x8 dAh0 = *(const s16x8*)(atpH + t0 + quad * 8);
        s16x8 dAl0 = *(const s16x8*)(atpL + t0 + quad * 8);
        s16x8 dAh1 = *(const s16x8*)(atpH + t0 + 32 + quad * 8);
        s16x8 dAl1 = *(const s16x8*)(atpL + t0 + 32 + quad * 8);

        unsigned* buf = xs[g & 1];
        f32x4 acc[4];
#pragma unroll
        for (int mt = 0; mt < 4; mt++) acc[mt] = (f32x4){0.f, 0.f, 0.f, 0.f};

#pragma unroll
        for (int mt = 0; mt < 4; mt++) {
            int rr = mt * 16 + lm;       // rr&7 == lm&7 -> swizzle sA
            int t = t0 + rr;
            const unsigned short* thp = twdH + (size_t)t * C + quad * 8;
            const unsigned short* tlp = twdL + (size_t)t * C + quad * 8;
            const unsigned* xrp = buf + rr * 64;
            int base0 = (quad * 8) ^ sA;
            s16x8 a;
            a = *(const s16x8*)thp;
            acc[mt] = __builtin_amdgcn_mfma_f32_16x16x32_bf16(a, bf0, acc[mt], 0, 0, 0);
            acc[mt] = __builtin_amdgcn_mfma_f32_16x16x32_bf16(a, bf4, acc[mt], 0, 0, 0);
            a = *(const s16x8*)(thp + 32);
            acc[mt] = __builtin_amdgcn_mfma_f32_16x16x32_bf16(a, bf1, acc[mt], 0, 0, 0);
            acc[mt] = __builtin_amdgcn_mfma_f32_16x16x32_bf16(a, bf5, acc[mt], 0, 0, 0);
            uint4 p0 = *(const uint4*)(xrp + base0);
            uint4 p1 = *(const uint4*)(xrp + (base0 ^ 4));
            a = hi8(p0, p1);
            acc[mt] = __builtin_amdgcn_mfma_f32_16x16x32_bf16(a, bf2, acc[mt], 0, 0, 0);
            acc[mt] = __builtin_amdgcn_mfma_f32_16x16x32_bf16(a, bf6, acc[mt], 0, 0, 0);
            uint4 p2 = *(const uint4*)(xrp + (base0 ^ 32));
            uint4 p3 = *(const uint4*)(xrp + (base0 ^ 36));
            a = hi8(p2, p3);
            acc[mt] = __builtin_amdgcn_mfma_f32_16x16x32_bf16(a, bf3, acc[mt], 0, 0, 0);
            acc[mt] = __builtin_amdgcn_mfma_f32_16x16x32_bf16(a, bf7, acc[mt], 0, 0, 0);
            a = *(const s16x8*)tlp;
            acc[mt] = __builtin_amdgcn_mfma_f32_16x16x32_bf16(a, bf0, acc[mt], 0, 0, 0);
            a = *(const s16x8*)(tlp + 32);
            acc[mt] = __builtin_amdgcn_mfma_f32_16x16x32_bf16(a, bf1, acc[mt], 0, 0, 0);
            a = lo8(p0, p1);
            acc[mt] = __builtin_amdgcn_mfma_f32_16x16x32_bf16(a, bf2, acc[mt], 0, 0, 0);
            a = lo8(p2, p3);
            acc[mt] = __builtin_amdgcn_mfma_f32_16x16x32_bf16(a, bf3, acc[mt], 0, 0, 0);
        }

        // epilogue COMPUTE (register-only) — hoisted above barrier 2 so it
        // overlaps other waves' conv-MFMA; acc dies as pv is born (VGPR-neutral)
        unsigned pv[4][4];
#pragma unroll
        for (int mt = 0; mt < 4; mt++)
#pragma unroll
            for (int r = 0; r < 4; r++)
                pv[mt][r] = pack_split(gelu_fast(acc[mt][r] + cbv));

        // barrier 2: all reads of buf done (LDS only; stores stay in flight)
        asm volatile("s_waitcnt lgkmcnt(0)\n\ts_barrier" ::: "memory");

        // staging for g+1 BEFORE the stores (makes vmcnt(16) at next top exact)
        if (g + 1 < GCHC) {
            const unsigned* nbase = cbase + (size_t)(g + 1) * 4096;
#pragma unroll
            for (int p = 0; p < 4; p++)
                __builtin_amdgcn_global_load_lds((gas_ptr)(nbase + soff[p]),
                                                 (las_ptr)(&xs[(g + 1) & 1][tid * 4 + p * 1024]),
                                                 16, 0, 0);
        }
        // store burst: global x stores (per WRITEX) + transposed swizzled LDS
#pragma unroll
        for (int mt = 0; mt < 4; mt++) {
#pragma unroll
            for (int r = 0; r < 4; r++) {
                int t = t0 + mt * 16 + quad * 4 + r;
                if (WRITEX) {
                    xp[(bT + t) * C + ncol] = pv[mt][r];
                } else if (t0 == T - 64) {
                    xp[(bT + t) * C + ncol] = pv[mt][r];
                }
            }
            uint4 pk;
            pk.x = pv[mt][0]; pk.y = pv[mt][1]; pk.z = pv[mt][2]; pk.w = pv[mt][3];
            *(uint4*)(&buf[ncol * 64 + ((mt * 16 + quad * 4) ^ sA)]) = pk;
        }
        // barrier 3: transpose visible (LDS only — stores remain in flight)
        asm volatile("s_waitcnt lgkmcnt(0)\n\ts_barrier" ::: "memory");

        // DFT partial over this chunk's NEW x (K=64); A from prefetched regs
#pragma unroll
        for (int ks = 0; ks < 2; ks++) {
            s16x8 ah = ks ? dAh1 : dAh0;
            s16x8 al = ks ? dAl1 : dAl0;
#pragma unroll
            for (int nt = 0; nt < 4; nt++) {
                int cd = nt * 16 + lm;   // cd&7 == lm&7 -> swizzle sA
                const unsigned* bpb = buf + cd * 64;
                int tb0 = (ks * 32 + quad * 8) ^ sA;
                uint4 b0 = *(const uint4*)(bpb + tb0);
                uint4 b1 = *(const uint4*)(bpb + (tb0 ^ 4));
                s16x8 bh = hi8(b0, b1), bl2 = lo8(b0, b1);
                dftacc[nt] = __builtin_amdgcn_mfma_f32_16x16x32_bf16(ah, bh, dftacc[nt], 0, 0, 0);
                dftacc[nt] = __builtin_amdgcn_mfma_f32_16x16x32_bf16(ah, bl2, dftacc[nt], 0, 0, 0);
                dftacc[nt] = __builtin_amdgcn_mfma_f32_16x16x32_bf16(al, bh, dftacc[nt], 0, 0, 0);
            }
        }
    }
    float sgn = (wv >= 2) ? -1.f : 1.f;
#pragma unroll
    for (int nt = 0; nt < 4; nt++)
#pragma unroll
        for (int r = 0; r < 4; r++) {
            int j = wv * 16 + quad * 4 + r;
            unsafeAtomicAdd(&partF[((size_t)b * 64 + j) * 64 + nt * 16 + lm],
                            sgn * dftacc[nt][r]);
        }
}

// Layer 3 at t=T-1 only, then fc1+gelu, fc2. grid B, 128 threads.
__global__ void final_k(const unsigned* __restrict__ x3, const float2* __restrict__ Y3,
                        const float* __restrict__ cw, const float* __restrict__ cb,
                        const float* __restrict__ w1, const float* __restrict__ b1,
                        const float* __restrict__ w2, const float* __restrict__ b2,
                        float* __restrict__ out) {
    int b = blockIdx.x, tid = threadIdx.x;
    __shared__ float xrow[C];
    __shared__ float xl[C];
    __shared__ float h[FC1N];
    if (tid < C) {
        unsigned u = x3[((size_t)b * T + (T - 1)) * C + tid];
        xrow[tid] = __uint_as_float(u & 0xFFFF0000u) + __uint_as_float(u << 16);
    }
    __syncthreads();
    if (tid < C) {
        int o = tid;
        const float2* Yb = Y3 + (size_t)b * (MODES * C);
        float a2 = 0.f;
        for (int k = 1; k < MODES; k++) {
            float thk = 7.6699039394282067e-4f * (float)k;
            float cwv = cosf(thk), swv = -sinf(thk);
            float2 y = Yb[k * C + o];
            a2 = fmaf(y.x, cwv, a2);
            a2 = fmaf(-y.y, swv, a2);
        }
        float xf = (Yb[o].x + 2.f * a2) * (1.0f / (float)T);
        float cv = cb[o];
        for (int c = 0; c < C; c++) cv = fmaf(xrow[c], cw[c * C + o], cv);
        xl[o] = gelu_exact(xf + cv);
    }
    __syncthreads();
    {
        int j = tid;
        float acc = b1[j];
        for (int c = 0; c < C; c++) acc = fmaf(xl[c], w1[c * FC1N + j], acc);
        h[j] = gelu_exact(acc);
    }
    __syncthreads();
    if (tid < OUTN) {
        float acc = b2[tid];
        for (int j = 0; j < FC1N; j++) acc = fmaf(h[j], w2[j * OUTN + tid], acc);
        out[b * OUTN + tid] = acc;
    }
}

extern "C" void kernel_launch(void* const* d_in, const int* in_sizes, int n_in,
                              void* d_out, int out_size, void* d_ws, size_t ws_size,
                              hipStream_t stream) {
    const float* inp   = (const float*)d_in[0];
    const float* fc0_w = (const float*)d_in[1];
    const float* fc0_b = (const float*)d_in[2];
    const float* fwr   = (const float*)d_in[3];
    const float* fwi   = (const float*)d_in[4];
    const float* cw    = (const float*)d_in[5];
    const float* cb    = (const float*)d_in[6];
    const float* w1    = (const float*)d_in[7];
    const float* b1    = (const float*)d_in[8];
    const float* w2    = (const float*)d_in[9];
    const float* b2    = (const float*)d_in[10];
    float* out = (float*)d_out;

    // Workspace layout (total 142,606,336 B <= proven 143,654,912)
    char* ws = (char*)d_ws;
    unsigned* x = (unsigned*)ws;                                  // 134,217,728
    size_t off = (size_t)B * T * C * sizeof(unsigned);
    float* partF = (float*)(ws + off);                            //   1,048,576
    const size_t PART_BYTES = (size_t)B * 64 * 64 * sizeof(float);
    off += PART_BYTES;
    float2* Y = (float2*)(ws + off);                              //   1,048,576
    off += (size_t)B * MODES * C * sizeof(float2);
    unsigned short* twdH = (unsigned short*)(ws + off);           //   1,048,576
    off += (size_t)T * C * sizeof(unsigned short);
    unsigned short* twdL = (unsigned short*)(ws + off);           //   1,048,576
    off += (size_t)T * C * sizeof(unsigned short);
    unsigned short* twdTPH = (unsigned short*)(ws + off);         //   1,048,576
    off += (size_t)64 * T * sizeof(unsigned short);
    unsigned short* twdTPL = (unsigned short*)(ws + off);         //   1,048,576
    off += (size_t)64 * T * sizeof(unsigned short);
    unsigned short* Bw = (unsigned short*)(ws + off);             //   2,097,152
    off += (size_t)B * C * 256 * sizeof(unsigned short);

    twdtab_k<<<(T * C) / 256, 256, 0, stream>>>(twdH, twdL);
    twdtabT_k<<<(64 * T) / 256, 256, 0, stream>>>(twdTPH, twdTPL);

    hipMemsetAsync(partF, 0, PART_BYTES, stream);
    fc0dft_k<<<dim3(T / (64 * GCHF), B), 256, 0, stream>>>(inp, fc0_w, fc0_b,
                                                           twdTPH, twdTPL, x, partF);

    for (int l = 0; l < 4; l++) {
        mixbw_k<<<dim3(B, 4), 256, 0, stream>>>(partF, fwr + (size_t)l * MODES * C * C,
                                                fwi + (size_t)l * MODES * C * C,
                                                cw + (size_t)l * C * C, Y, Bw,
                                                (l < 3) ? 1 : 0);
        if (l < 3) {
            hipMemsetAsync(partF, 0, PART_BYTES, stream);
            if (l == 2)
                combine_mfma<0><<<dim3(T / (64 * GCHC), B), 256, 0, stream>>>(
                    x, twdH, twdL, twdTPH, twdTPL, Bw, cb + (size_t)l * C, partF);
            else
                combine_mfma<1><<<dim3(T / (64 * GCHC), B), 256, 0, stream>>>(
                    x, twdH, twdL, twdTPH, twdTPL, Bw, cb + (size_t)l * C, partF);
        }
    }
    final_k<<<B, FC1N, 0, stream>>>(x, Y, cw + (size_t)3 * C * C, cb + (size_t)3 * C,
                                    w1, b1, w2, b2, out);
}